// Round 1
// baseline (34.040 us; speedup 1.0000x reference)
//
#include <hip/hip_runtime.h>

// OneDimEquivalent: sequential nonlinear scan, parallelized via contraction
// (warm-up windows) + LDS lookup table for the 64-node Gauss-Legendre integral.
//
// Reference step (all fp32):
//   delta^2 = 1.44*k^2 + 0.64*u^2
//   gi      = sum_j Qw_j * (1 - tanh(delta*Qz_j)^2) * exp(-Qz_j^2/2) / (2*pi)
//   k_new   = 0.8*k + 0.2*gi*(0.9*k + 0.5*v)      (contraction factor <= 0.872)
//   v_new   = 0.8*v + 0.2*u                        (contraction factor 0.8)
//   z       = 0.7*gi*k_new
//
// gi is a smooth function of s = delta^2 -> 4097-entry table over s in [0,32),
// linear interp (err ~1.2e-5 << 1.02e-3 threshold). Table built on-device from
// fp64-Newton Gauss-Legendre nodes so it matches the reference quadrature.

#define N_TAB   4096          // table entries over s = delta^2 in [0, 32)
#define W_STEPS 128           // warm-up steps: 0.872^128 ~ 2.6e-8 residual
#define CHUNK   4             // z outputs per thread
#define THREADS 256

// ---------------- Gauss-Legendre order-64 nodes/weights (per-block, fp64) ---
__device__ __forceinline__ void gl_nodes_block(double* zs, double* wc) {
  __shared__ double rinv[65];
  const int tid = threadIdx.x;
  if (tid >= 2 && tid <= 64) rinv[tid] = 1.0 / (double)tid;
  __syncthreads();
  if (tid < 64) {
    // Newton on P_64; standard gauleg initial guess, quadratic convergence.
    double x = cos(3.14159265358979323846 * ((double)tid + 0.75) / 64.5);
    double dp = 1.0;
    for (int it = 0; it < 5; ++it) {
      double p0 = 1.0, p1 = x;
      for (int j = 2; j <= 64; ++j) {
        double p2 = ((2.0 * j - 1.0) * x * p1 - (double)(j - 1) * p0) * rinv[j];
        p0 = p1; p1 = p2;
      }
      dp = 64.0 * (x * p1 - p0) / (x * x - 1.0);
      x -= p1 / dp;
    }
    double w = 2.0 / ((1.0 - x * x) * dp * dp);
    // Match reference exactly: nodes/weights scaled by A=5 then cast to fp32.
    float zn = (float)(5.0 * x);
    float wn = (float)(5.0 * w);
    zs[tid] = (double)zn;
    // fold weight * exp(-z^2/2) / (2*pi) into one coefficient
    wc[tid] = (double)wn * exp(-0.5 * (double)zn * (double)zn)
              * 0.15915494309189535;  // 1/(2*pi)
  }
  __syncthreads();
}

// gi at s = idx/128 (delta = sqrt(s)), 64-node sum; sech^2 in fp32, fp64 accum.
__device__ __forceinline__ float table_entry(int idx, const double* zs,
                                             const double* wc) {
  double d = sqrt((double)idx * (1.0 / 128.0));
  double acc = 0.0;
  for (int j = 0; j < 64; ++j) {
    float x2 = (float)(2.0 * d * zs[j]);     // 2*delta*z_j
    float e  = __expf(-fabsf(x2));           // e^{-2|x|}
    float t  = 1.0f + e;
    acc += wc[j] * (double)(4.0f * e / (t * t));   // sech^2 = 4e/(1+e)^2
  }
  return (float)acc;
}

__global__ void build_table_kernel(float* __restrict__ tabg) {
  __shared__ double zs[64], wc[64];
  gl_nodes_block(zs, wc);
  for (int idx = blockIdx.x * blockDim.x + threadIdx.x; idx <= N_TAB;
       idx += gridDim.x * blockDim.x)
    tabg[idx] = table_entry(idx, zs, wc);
}

// ---------------- main scan --------------------------------------------------
__device__ __forceinline__ float step(float& k, float& v, float uu,
                                      const float* tab) {
  float s  = fmaf(1.44f * k, k, 0.64f * uu * uu);   // delta^2
  float x  = fminf(s * 128.0f, 4095.99f);           // table coordinate
  int   i  = (int)x;
  float f  = x - (float)i;
  float g0 = tab[i];
  float g1 = tab[i + 1];
  float gi = fmaf(f, g1 - g0, g0);
  float kn = fmaf(0.2f * gi, fmaf(0.9f, k, 0.5f * v), 0.8f * k);
  v = fmaf(0.2f, uu, 0.8f * v);
  k = kn;
  return 0.7f * gi * kn;
}

template <bool BUILD>
__global__ __launch_bounds__(THREADS, 2) void scan_kernel(
    const float* __restrict__ u, const float* __restrict__ tabg,
    float* __restrict__ out) {
  __shared__ float tab[N_TAB + 1];
  if constexpr (BUILD) {
    __shared__ double zs[64], wc[64];
    gl_nodes_block(zs, wc);
    for (int i = threadIdx.x; i <= N_TAB; i += THREADS)
      tab[i] = table_entry(i, zs, wc);
  } else {
    for (int i = threadIdx.x; i <= N_TAB; i += THREADS) tab[i] = tabg[i];
  }
  __syncthreads();

  const int t      = blockIdx.x * THREADS + threadIdx.x;  // chunk id
  const int g4     = t * CHUNK;                           // first z index
  const int wsteps = min(W_STEPS, g4);                    // multiple of 4
  const int ngrp   = wsteps >> 2;
  const float4* __restrict__ up = (const float4*)(u + (g4 - wsteps));

  float k = 0.0f, v = 0.0f;
  float4 cur = up[0];
  for (int g = 0; g < ngrp; ++g) {        // warm-up: converge to true state
    float4 nxt = up[g + 1];               // prefetch next 4 inputs
    step(k, v, cur.x, tab);
    step(k, v, cur.y, tab);
    step(k, v, cur.z, tab);
    step(k, v, cur.w, tab);
    cur = nxt;
  }
  float z0 = step(k, v, cur.x, tab);      // emit chunk outputs
  float z1 = step(k, v, cur.y, tab);
  float z2 = step(k, v, cur.z, tab);
  float z3 = step(k, v, cur.w, tab);
  out[g4 + 1] = z0;
  out[g4 + 2] = z1;
  out[g4 + 3] = z2;
  out[g4 + 4] = z3;
  if (t == 0) out[0] = 0.0f;              // z_hist[0] = 0
}

extern "C" void kernel_launch(void* const* d_in, const int* in_sizes, int n_in,
                              void* d_out, int out_size, void* d_ws,
                              size_t ws_size, hipStream_t stream) {
  const float* u = (const float*)d_in[0];
  float* out = (float*)d_out;
  const int T = in_sizes[0];                       // 524288
  const int nblock = T / (CHUNK * THREADS);        // 512

  if (d_ws && ws_size >= (N_TAB + 1) * sizeof(float)) {
    float* tabg = (float*)d_ws;
    build_table_kernel<<<32, 128, 0, stream>>>(tabg);
    scan_kernel<false><<<nblock, THREADS, 0, stream>>>(u, tabg, out);
  } else {
    scan_kernel<true><<<nblock, THREADS, 0, stream>>>(u, nullptr, out);
  }
}